// Round 22
// baseline (187.234 us; speedup 1.0000x reference)
//
#include <hip/hip_runtime.h>
#include <hip/hip_fp16.h>
#include <stdint.h>

#define NB 4
#define SS 192
#define NI 256

typedef __attribute__((ext_vector_type(8))) _Float16 f16x8;
typedef __attribute__((ext_vector_type(2))) __fp16 fp16v2;
typedef __attribute__((ext_vector_type(16))) float f32x16;

__device__ __forceinline__ uint16_t f2h(float f) {
  union { _Float16 h; uint16_t u; } t; t.h = (_Float16)f; return t.u;
}

__device__ __forceinline__ uint32_t cvt2(float lo, float hi) {
  union { fp16v2 h; uint32_t u; } t;
  t.h = __builtin_amdgcn_cvt_pkrtz(lo, hi);
  return t.u;
}

// pack 8 f32 -> 8 fp16 (4 x v_cvt_pkrtz)
__device__ __forceinline__ uint4 pack8h(const float4 a, const float4 b) {
  uint4 r;
  r.x = cvt2(a.x, a.y);
  r.y = cvt2(a.z, a.w);
  r.z = cvt2(b.x, b.y);
  r.w = cvt2(b.z, b.w);
  return r;
}

// packed fp16 multiply: 1 x v_pk_mul_f16
__device__ __forceinline__ uint32_t hmul2(uint32_t x, uint32_t y) {
  union { uint32_t u; __half2 h; } a, b, c;
  a.u = x; b.u = y;
  c.h = __hmul2(a.h, b.h);
  return c.u;
}

// Canonical fp16 storage: row-major, 8-elem chunk c stored at position c ^ (row&15).
// partial[] contract: 2048 chunks of 8192 floats; w_red[i] = sum(partial[8i..8i+7]).

// ---------------- K_A: s1-blocks (0..23) + HH/HD/HS converts (24..119) + W partials (120..2167) ----------------
__global__ __launch_bounds__(256) void kA(
    const float* __restrict__ W,
    const float* __restrict__ h_head, const float* __restrict__ h_dep, const float* __restrict__ h_sib,
    const float* __restrict__ U, const float* __restrict__ V, const float* __restrict__ Z,
    float* __restrict__ partial,
    uint16_t* __restrict__ HH, uint16_t* __restrict__ HD, uint16_t* __restrict__ HS,
    uint16_t* __restrict__ dU16, uint16_t* __restrict__ T216, uint16_t* __restrict__ TZ16) {
  const int bi = blockIdx.x, tid = threadIdx.x;

  if (bi >= 120) {
    __shared__ float red[4];
    const int c = bi - 120;
    const float4* pw = (const float4*)(W + (size_t)c * 8192);
    float4 a = {0.f, 0.f, 0.f, 0.f};
    #pragma unroll
    for (int it = 0; it < 8; ++it) {
      const float4 v = pw[it * 256 + tid];
      a.x += v.x; a.y += v.y; a.z += v.z; a.w += v.w;
    }
    float s = (a.x + a.y) + (a.z + a.w);
    for (int off = 32; off > 0; off >>= 1) s += __shfl_down(s, off, 64);
    if ((tid & 63) == 0) red[tid >> 6] = s;
    __syncthreads();
    if (tid == 0) partial[c] = red[0] + red[1] + red[2] + red[3];
    return;
  }
  if (bi >= 24) {
    const int rl = tid >> 5, c8 = tid & 31;
    const int g = (bi - 24) * 8 + rl;              // 0..767
    const int dst = g * 32 + (c8 ^ (g & 15));
    const int srci = g * 64 + c8 * 2;
    { const float4 x = ((const float4*)h_head)[srci], y = ((const float4*)h_head)[srci + 1];
      ((uint4*)HH)[dst] = pack8h(x, y); }
    { const float4 x = ((const float4*)h_dep)[srci], y = ((const float4*)h_dep)[srci + 1];
      ((uint4*)HD)[dst] = pack8h(x, y); }
    { const float4 x = ((const float4*)h_sib)[srci], y = ((const float4*)h_sib)[srci + 1];
      ((uint4*)HS)[dst] = pack8h(x, y); }
    return;
  }

  // ---- s1 block: dU/T2/TZ = A(192xK) x B(U/V/Z rows)^T, self-converting staging ----
  {
    __shared__ __align__(16) uint16_t Ah[192 * 128];   // 48 KB
    __shared__ __align__(16) uint16_t Bh[128 * 128];   // 32 KB
    const int which = bi >> 3, rem = bi & 7;
    const int b = rem >> 1, nt = rem & 1;
    const float* As = (which == 0) ? h_dep : h_sib;
    const float* Bs = (which == 0) ? U : (which == 1) ? V : Z;
    uint16_t* Os = (which == 0) ? dU16 : (which == 1) ? T216 : TZ16;
    const int lane = tid & 63, w = tid >> 6;
    const int l31 = lane & 31, l5 = lane >> 5;
    const int N0 = nt * 128;
    f32x16 acc[6] = {};

    #pragma unroll
    for (int kh = 0; kh < 2; ++kh) {
      const int kbase = kh * 128;
      if (kh) __syncthreads();
      #pragma unroll
      for (int i = 0; i < 12; ++i) {
        const int slot = i * 256 + tid;
        const int row = slot >> 4, ck = slot & 15;
        const float* sp = As + (size_t)(b * SS + row) * NI + kbase + ck * 8;
        const float4 x = *(const float4*)sp, y = *(const float4*)(sp + 4);
        *(uint4*)((char*)Ah + row * 256 + ((ck ^ (row & 15)) << 4)) = pack8h(x, y);
      }
      #pragma unroll
      for (int i = 0; i < 8; ++i) {
        const int slot = i * 256 + tid;
        const int row = slot >> 4, ck = slot & 15;
        const float* sp = Bs + (size_t)(N0 + row) * NI + kbase + ck * 8;
        const float4 x = *(const float4*)sp, y = *(const float4*)(sp + 4);
        *(uint4*)((char*)Bh + row * 256 + ((ck ^ (row & 15)) << 4)) = pack8h(x, y);
      }
      __syncthreads();
      const int brow = w * 32 + l31;
      const int bbyte = brow * 256;
      const int bmask = brow & 15;
      #pragma unroll
      for (int ks = 0; ks < 8; ++ks) {
        const int sl = ks * 2 + l5;
        f16x8 bf = *reinterpret_cast<const f16x8*>((const char*)Bh + bbyte + ((sl ^ bmask) << 4));
        #pragma unroll
        for (int mt = 0; mt < 6; ++mt) {
          const int ar = mt * 32 + l31;
          f16x8 af = *reinterpret_cast<const f16x8*>((const char*)Ah + ar * 256 + ((sl ^ (ar & 15)) << 4));
          acc[mt] = __builtin_amdgcn_mfma_f32_32x32x16_f16(af, bf, acc[mt], 0, 0, 0);
        }
      }
    }
    const int n = N0 + w * 32 + l31;
    const int nck = n >> 3, npos = n & 7;
    #pragma unroll
    for (int mt = 0; mt < 6; ++mt) {
      #pragma unroll
      for (int r = 0; r < 16; ++r) {
        const int m = mt * 32 + (r & 3) + 8 * (r >> 2) + 4 * l5;
        Os[(size_t)(b * SS + m) * NI + ((nck ^ (m & 15)) << 3) + npos] = f2h(acc[mt][r]);
      }
    }
  }
}

// ---------------- K2 stage-2: s_hd/s_hs/s_ds (192x192, K=256), MFMA ----------------
__global__ __launch_bounds__(384, 1) void k_s2(
    const uint16_t* __restrict__ HH, const uint16_t* __restrict__ HD,
    const uint16_t* __restrict__ dU16, const uint16_t* __restrict__ T216, const uint16_t* __restrict__ TZ16,
    float* __restrict__ s_hd, float* __restrict__ s_hs, float* __restrict__ s_ds) {
  __shared__ __align__(16) uint16_t Ah[192 * 128];   // 48 KB
  __shared__ __align__(16) uint16_t Bh[192 * 128];   // 48 KB
  const int which = blockIdx.x, b = blockIdx.y;
  const uint16_t* As = (which == 2) ? HD : HH;
  const uint16_t* Bs = (which == 0) ? dU16 : (which == 1) ? T216 : TZ16;
  float* Os = (which == 0) ? s_hd : (which == 1) ? s_hs : s_ds;
  const int tid = threadIdx.x, lane = tid & 63, w = tid >> 6;
  const int l31 = lane & 31, l5 = lane >> 5;
  f32x16 acc[6] = {};

  #pragma unroll
  for (int kh = 0; kh < 2; ++kh) {
    const int kbase = kh * 128;
    if (kh) __syncthreads();
    #pragma unroll
    for (int i = 0; i < 8; ++i) {
      const int slot = i * 384 + tid;
      const int row = slot >> 4, ck = slot & 15;
      const uint16_t* src = As + (size_t)(b * SS + row) * NI + kbase + ck * 8;
      __builtin_amdgcn_global_load_lds((const __attribute__((address_space(1))) void*)src,
          (__attribute__((address_space(3))) void*)(Ah + (size_t)slot * 8), 16, 0, 0);
    }
    #pragma unroll
    for (int i = 0; i < 8; ++i) {
      const int slot = i * 384 + tid;
      const int row = slot >> 4, ck = slot & 15;
      const uint16_t* src = Bs + (size_t)(b * SS + row) * NI + kbase + ck * 8;
      __builtin_amdgcn_global_load_lds((const __attribute__((address_space(1))) void*)src,
          (__attribute__((address_space(3))) void*)(Bh + (size_t)slot * 8), 16, 0, 0);
    }
    __syncthreads();
    const int brow = w * 32 + l31;
    const int bbyte = brow * 256;
    const int bmask = brow & 15;
    #pragma unroll
    for (int ks = 0; ks < 8; ++ks) {
      const int sl = ks * 2 + l5;
      f16x8 bf = *reinterpret_cast<const f16x8*>((const char*)Bh + bbyte + ((sl ^ bmask) << 4));
      #pragma unroll
      for (int mt = 0; mt < 6; ++mt) {
        const int ar = mt * 32 + l31;
        f16x8 af = *reinterpret_cast<const f16x8*>((const char*)Ah + ar * 256 + ((sl ^ (ar & 15)) << 4));
        acc[mt] = __builtin_amdgcn_mfma_f32_32x32x16_f16(af, bf, acc[mt], 0, 0, 0);
      }
    }
  }
  const int n = w * 32 + l31;
  #pragma unroll
  for (int mt = 0; mt < 6; ++mt) {
    #pragma unroll
    for (int r = 0; r < 16; ++r) {
      const int m = mt * 32 + (r & 3) + 8 * (r >> 2) + 4 * l5;
      Os[(size_t)(b * SS + m) * SS + n] = acc[mt][r];
    }
  }
}

// ---------------- K3: main GEMM — 96h x 96s, 9 waves, chd_s; fp16 packed A-build ----------------
__global__ __launch_bounds__(576) void k3_big(
    const uint16_t* __restrict__ HH, const uint16_t* __restrict__ HS,
    const float* __restrict__ h_dep, const float* __restrict__ partial,
    const float* __restrict__ s_hd, const float* __restrict__ s_hs,
    const float* __restrict__ s_ds,
    const float* __restrict__ bias, float* __restrict__ out) {
  __shared__ __align__(16) uint16_t Btile[96 * 128];   // 24 KB
  __shared__ __align__(16) uint16_t Atile[96 * 128];   // 24 KB
  __shared__ uint16_t cvec[NI];
  __shared__ float chd_s[96];
  const int d = blockIdx.x, hb = blockIdx.y >> 1, sb = blockIdx.y & 1, b = blockIdx.z;
  const int tid = threadIdx.x;
  const int lane = tid & 63, w = tid >> 6;
  const int wh = w / 3, ws = w % 3;
  const int l31 = lane & 31, l5 = lane >> 5;

  if (tid < NI) {
    float wr = 0.f;
    #pragma unroll
    for (int q = 0; q < 8; ++q) wr += partial[8 * tid + q];
    cvec[tid] = f2h(wr * h_dep[(b * SS + d) * NI + tid]);
  } else if (tid < NI + 96) {
    const int t = tid - NI;
    chd_s[t] = s_hd[(size_t)(b * SS + hb * 96 + t) * SS + d];
  }
  __syncthreads();

  f32x16 acc = {};

  #pragma unroll
  for (int half = 0; half < 2; ++half) {
    const int kbase = half * 128;
    if (half) __syncthreads();
    #pragma unroll
    for (int i = 0; i < 3; ++i) {
      const int slot = i * 576 + tid;
      if (slot < 1536) {
        const int row = slot >> 4;
        const uint16_t* src = HS + ((size_t)(b * SS + sb * 96 + row) << 8) + kbase + (slot & 15) * 8;
        __builtin_amdgcn_global_load_lds(
            (const __attribute__((address_space(1))) void*)src,
            (__attribute__((address_space(3))) void*)(Btile + (size_t)slot * 8),
            16, 0, 0);
      }
    }
    #pragma unroll
    for (int i = 0; i < 3; ++i) {
      const int slot = i * 576 + tid;
      if (slot < 1536) {
        const int row = slot >> 4;
        const int kc = slot & 15;
        const int lcl = kc ^ (row & 15);
        const uint4 cv4 = *(const uint4*)(cvec + kbase + lcl * 8);
        const uint4 hh4 = *(const uint4*)(HH + ((size_t)(b * SS + hb * 96 + row) << 8) + kbase + kc * 8);
        uint4 a4;
        a4.x = hmul2(hh4.x, cv4.x);
        a4.y = hmul2(hh4.y, cv4.y);
        a4.z = hmul2(hh4.z, cv4.z);
        a4.w = hmul2(hh4.w, cv4.w);
        *(uint4*)((char*)Atile + (size_t)slot * 16) = a4;
      }
    }
    __syncthreads();
    const int arow = wh * 32 + l31;
    const int abyte = arow * 256;
    const int amask = arow & 15;
    const int brow = ws * 32 + l31;
    const int bbyte = brow * 256;
    const int bmask = brow & 15;
    #pragma unroll
    for (int ks = 0; ks < 8; ++ks) {
      const int sl = ks * 2 + l5;
      f16x8 af = *reinterpret_cast<const f16x8*>((const char*)Atile + abyte + ((sl ^ amask) << 4));
      f16x8 bf = *reinterpret_cast<const f16x8*>((const char*)Btile + bbyte + ((sl ^ bmask) << 4));
      acc = __builtin_amdgcn_mfma_f32_32x32x16_f16(af, bf, acc, 0, 0, 0);
    }
  }

  const float bias0 = bias[0];
  const int s = sb * 96 + ws * 32 + l31;
  const float dsv = s_ds[(b * SS + d) * SS + s];
  #pragma unroll
  for (int r = 0; r < 16; ++r) {
    const int hl = wh * 32 + (r & 3) + 8 * (r >> 2) + 4 * l5;
    const float v = acc[r] + chd_s[hl] + bias0
                  + s_hs[(size_t)(b * SS + hb * 96 + hl) * SS + s] + dsv;
    out[((size_t)(b * SS + hb * 96 + hl) * SS + d) * SS + s] = v;
  }
}

extern "C" void kernel_launch(void* const* d_in, const int* in_sizes, int n_in,
                              void* d_out, int out_size, void* d_ws, size_t ws_size,
                              hipStream_t stream) {
  const float* h_head = (const float*)d_in[0];
  const float* h_dep  = (const float*)d_in[1];
  const float* h_sib  = (const float*)d_in[2];
  const float* W_tri  = (const float*)d_in[3];
  const float* U_hd   = (const float*)d_in[4];
  const float* V_hs   = (const float*)d_in[5];
  const float* Z_ds   = (const float*)d_in[6];
  const float* bias   = (const float*)d_in[7];
  float* out = (float*)d_out;

  float* ws = (float*)d_ws;
  float* partial = ws;          ws += 2048;
  float* s_hd    = ws;          ws += NB * SS * SS;
  float* s_hs    = ws;          ws += NB * SS * SS;
  float* s_ds    = ws;          ws += NB * SS * SS;
  uint16_t* HH   = (uint16_t*)ws;
  uint16_t* HD   = HH + NB * SS * NI;
  uint16_t* HS   = HD + NB * SS * NI;
  uint16_t* dU16 = HS + NB * SS * NI;
  uint16_t* T216 = dU16 + NB * SS * NI;
  uint16_t* TZ16 = T216 + NB * SS * NI;

  kA<<<2168, 256, 0, stream>>>(W_tri, h_head, h_dep, h_sib, U_hd, V_hs, Z_ds,
                               partial, HH, HD, HS, dU16, T216, TZ16);
  k_s2<<<dim3(3, NB), 384, 0, stream>>>(HH, HD, dU16, T216, TZ16, s_hd, s_hs, s_ds);
  // DIAGNOSTIC: k3 launched 4x (idempotent — pure function of inputs).
  // k3_dur = (dur_us - 65.5) / 3. Remove duplicates next round.
  k3_big<<<dim3(SS, 4, NB), 576, 0, stream>>>(HH, HS, h_dep, partial,
                                              s_hd, s_hs, s_ds, bias, out);
  k3_big<<<dim3(SS, 4, NB), 576, 0, stream>>>(HH, HS, h_dep, partial,
                                              s_hd, s_hs, s_ds, bias, out);
  k3_big<<<dim3(SS, 4, NB), 576, 0, stream>>>(HH, HS, h_dep, partial,
                                              s_hd, s_hs, s_ds, bias, out);
  k3_big<<<dim3(SS, 4, NB), 576, 0, stream>>>(HH, HS, h_dep, partial,
                                              s_hd, s_hs, s_ds, bias, out);
}

// Round 23
// 75.060 us; speedup vs baseline: 2.4945x; 2.4945x over previous
//
#include <hip/hip_runtime.h>
#include <hip/hip_fp16.h>
#include <stdint.h>

#define NB 4
#define SS 192
#define NI 256

typedef __attribute__((ext_vector_type(8))) _Float16 f16x8;
typedef __attribute__((ext_vector_type(2))) __fp16 fp16v2;
typedef __attribute__((ext_vector_type(16))) float f32x16;

__device__ __forceinline__ uint16_t f2h(float f) {
  union { _Float16 h; uint16_t u; } t; t.h = (_Float16)f; return t.u;
}

__device__ __forceinline__ uint32_t cvt2(float lo, float hi) {
  union { fp16v2 h; uint32_t u; } t;
  t.h = __builtin_amdgcn_cvt_pkrtz(lo, hi);
  return t.u;
}

__device__ __forceinline__ uint4 pack8h(const float4 a, const float4 b) {
  uint4 r;
  r.x = cvt2(a.x, a.y);
  r.y = cvt2(a.z, a.w);
  r.z = cvt2(b.x, b.y);
  r.w = cvt2(b.z, b.w);
  return r;
}

__device__ __forceinline__ uint32_t hmul2(uint32_t x, uint32_t y) {
  union { uint32_t u; __half2 h; } a, b, c;
  a.u = x; b.u = y;
  c.h = __hmul2(a.h, b.h);
  return c.u;
}

// Canonical fp16 storage: row-major, 8-elem chunk c stored at position c ^ (row&15).
// (Each 128-col half is a closed permutation -> linear copy of a half preserves it.)
// partial[] contract: 2048 chunks of 8192 floats; w_red[i] = sum(partial[8i..8i+7]).

// ---------------- K_A: s1-blocks (0..23) + HH/HD/HS converts (24..119) + W partials (120..2167) ----------------
__global__ __launch_bounds__(256) void kA(
    const float* __restrict__ W,
    const float* __restrict__ h_head, const float* __restrict__ h_dep, const float* __restrict__ h_sib,
    const float* __restrict__ U, const float* __restrict__ V, const float* __restrict__ Z,
    float* __restrict__ partial,
    uint16_t* __restrict__ HH, uint16_t* __restrict__ HD, uint16_t* __restrict__ HS,
    uint16_t* __restrict__ dU16, uint16_t* __restrict__ T216, uint16_t* __restrict__ TZ16) {
  const int bi = blockIdx.x, tid = threadIdx.x;

  if (bi >= 120) {
    __shared__ float red[4];
    const int c = bi - 120;
    const float4* pw = (const float4*)(W + (size_t)c * 8192);
    float4 a = {0.f, 0.f, 0.f, 0.f};
    #pragma unroll
    for (int it = 0; it < 8; ++it) {
      const float4 v = pw[it * 256 + tid];
      a.x += v.x; a.y += v.y; a.z += v.z; a.w += v.w;
    }
    float s = (a.x + a.y) + (a.z + a.w);
    for (int off = 32; off > 0; off >>= 1) s += __shfl_down(s, off, 64);
    if ((tid & 63) == 0) red[tid >> 6] = s;
    __syncthreads();
    if (tid == 0) partial[c] = red[0] + red[1] + red[2] + red[3];
    return;
  }
  if (bi >= 24) {
    const int rl = tid >> 5, c8 = tid & 31;
    const int g = (bi - 24) * 8 + rl;              // 0..767
    const int dst = g * 32 + (c8 ^ (g & 15));
    const int srci = g * 64 + c8 * 2;
    { const float4 x = ((const float4*)h_head)[srci], y = ((const float4*)h_head)[srci + 1];
      ((uint4*)HH)[dst] = pack8h(x, y); }
    { const float4 x = ((const float4*)h_dep)[srci], y = ((const float4*)h_dep)[srci + 1];
      ((uint4*)HD)[dst] = pack8h(x, y); }
    { const float4 x = ((const float4*)h_sib)[srci], y = ((const float4*)h_sib)[srci + 1];
      ((uint4*)HS)[dst] = pack8h(x, y); }
    return;
  }

  // ---- s1 block: dU/T2/TZ = A(192xK) x B(U/V/Z rows)^T, self-converting staging ----
  {
    __shared__ __align__(16) uint16_t Ah[192 * 128];   // 48 KB
    __shared__ __align__(16) uint16_t Bh[128 * 128];   // 32 KB
    const int which = bi >> 3, rem = bi & 7;
    const int b = rem >> 1, nt = rem & 1;
    const float* As = (which == 0) ? h_dep : h_sib;
    const float* Bs = (which == 0) ? U : (which == 1) ? V : Z;
    uint16_t* Os = (which == 0) ? dU16 : (which == 1) ? T216 : TZ16;
    const int lane = tid & 63, w = tid >> 6;
    const int l31 = lane & 31, l5 = lane >> 5;
    const int N0 = nt * 128;
    f32x16 acc[6] = {};

    #pragma unroll
    for (int kh = 0; kh < 2; ++kh) {
      const int kbase = kh * 128;
      if (kh) __syncthreads();
      #pragma unroll
      for (int i = 0; i < 12; ++i) {
        const int slot = i * 256 + tid;
        const int row = slot >> 4, ck = slot & 15;
        const float* sp = As + (size_t)(b * SS + row) * NI + kbase + ck * 8;
        const float4 x = *(const float4*)sp, y = *(const float4*)(sp + 4);
        *(uint4*)((char*)Ah + row * 256 + ((ck ^ (row & 15)) << 4)) = pack8h(x, y);
      }
      #pragma unroll
      for (int i = 0; i < 8; ++i) {
        const int slot = i * 256 + tid;
        const int row = slot >> 4, ck = slot & 15;
        const float* sp = Bs + (size_t)(N0 + row) * NI + kbase + ck * 8;
        const float4 x = *(const float4*)sp, y = *(const float4*)(sp + 4);
        *(uint4*)((char*)Bh + row * 256 + ((ck ^ (row & 15)) << 4)) = pack8h(x, y);
      }
      __syncthreads();
      const int brow = w * 32 + l31;
      const int bbyte = brow * 256;
      const int bmask = brow & 15;
      #pragma unroll
      for (int ks = 0; ks < 8; ++ks) {
        const int sl = ks * 2 + l5;
        f16x8 bf = *reinterpret_cast<const f16x8*>((const char*)Bh + bbyte + ((sl ^ bmask) << 4));
        #pragma unroll
        for (int mt = 0; mt < 6; ++mt) {
          const int ar = mt * 32 + l31;
          f16x8 af = *reinterpret_cast<const f16x8*>((const char*)Ah + ar * 256 + ((sl ^ (ar & 15)) << 4));
          acc[mt] = __builtin_amdgcn_mfma_f32_32x32x16_f16(af, bf, acc[mt], 0, 0, 0);
        }
      }
    }
    const int n = N0 + w * 32 + l31;
    const int nck = n >> 3, npos = n & 7;
    #pragma unroll
    for (int mt = 0; mt < 6; ++mt) {
      #pragma unroll
      for (int r = 0; r < 16; ++r) {
        const int m = mt * 32 + (r & 3) + 8 * (r >> 2) + 4 * l5;
        Os[(size_t)(b * SS + m) * NI + ((nck ^ (m & 15)) << 3) + npos] = f2h(acc[mt][r]);
      }
    }
  }
}

// ---------------- K2 stage-2: s_hd/s_hs/s_ds (192x192, K=256), MFMA ----------------
__global__ __launch_bounds__(384, 1) void k_s2(
    const uint16_t* __restrict__ HH, const uint16_t* __restrict__ HD,
    const uint16_t* __restrict__ dU16, const uint16_t* __restrict__ T216, const uint16_t* __restrict__ TZ16,
    float* __restrict__ s_hd, float* __restrict__ s_hs, float* __restrict__ s_ds) {
  __shared__ __align__(16) uint16_t Ah[192 * 128];   // 48 KB
  __shared__ __align__(16) uint16_t Bh[192 * 128];   // 48 KB
  const int which = blockIdx.x, b = blockIdx.y;
  const uint16_t* As = (which == 2) ? HD : HH;
  const uint16_t* Bs = (which == 0) ? dU16 : (which == 1) ? T216 : TZ16;
  float* Os = (which == 0) ? s_hd : (which == 1) ? s_hs : s_ds;
  const int tid = threadIdx.x, lane = tid & 63, w = tid >> 6;
  const int l31 = lane & 31, l5 = lane >> 5;
  f32x16 acc[6] = {};

  #pragma unroll
  for (int kh = 0; kh < 2; ++kh) {
    const int kbase = kh * 128;
    if (kh) __syncthreads();
    #pragma unroll
    for (int i = 0; i < 8; ++i) {
      const int slot = i * 384 + tid;
      const int row = slot >> 4, ck = slot & 15;
      const uint16_t* src = As + (size_t)(b * SS + row) * NI + kbase + ck * 8;
      __builtin_amdgcn_global_load_lds((const __attribute__((address_space(1))) void*)src,
          (__attribute__((address_space(3))) void*)(Ah + (size_t)slot * 8), 16, 0, 0);
    }
    #pragma unroll
    for (int i = 0; i < 8; ++i) {
      const int slot = i * 384 + tid;
      const int row = slot >> 4, ck = slot & 15;
      const uint16_t* src = Bs + (size_t)(b * SS + row) * NI + kbase + ck * 8;
      __builtin_amdgcn_global_load_lds((const __attribute__((address_space(1))) void*)src,
          (__attribute__((address_space(3))) void*)(Bh + (size_t)slot * 8), 16, 0, 0);
    }
    __syncthreads();
    const int brow = w * 32 + l31;
    const int bbyte = brow * 256;
    const int bmask = brow & 15;
    #pragma unroll
    for (int ks = 0; ks < 8; ++ks) {
      const int sl = ks * 2 + l5;
      f16x8 bf = *reinterpret_cast<const f16x8*>((const char*)Bh + bbyte + ((sl ^ bmask) << 4));
      #pragma unroll
      for (int mt = 0; mt < 6; ++mt) {
        const int ar = mt * 32 + l31;
        f16x8 af = *reinterpret_cast<const f16x8*>((const char*)Ah + ar * 256 + ((sl ^ (ar & 15)) << 4));
        acc[mt] = __builtin_amdgcn_mfma_f32_32x32x16_f16(af, bf, acc[mt], 0, 0, 0);
      }
    }
  }
  const int n = w * 32 + l31;
  #pragma unroll
  for (int mt = 0; mt < 6; ++mt) {
    #pragma unroll
    for (int r = 0; r < 16; ++r) {
      const int m = mt * 32 + (r & 3) + 8 * (r >> 2) + 4 * l5;
      Os[(size_t)(b * SS + m) * SS + n] = acc[mt][r];
    }
  }
}

// ---------------- K3: persistent-tile d-loop GEMM, barrier-free steady state ----------------
// grid (48, 4, 4): x = d-quad, y = (hb<<1)|sb, z = b. 576 thr = 9 waves (3h x 3s).
// LDS: HHt[96][256] + HSt[96][256] fp16 full-K (canonical swizzle preserved by
// linear copy), cvec4 (wred*HD rows, 4 d's), chd4, sds4. No barriers in d-loop:
// af = HHt-frag * cvec4-frag built on the fly (cv read is lane-broadcast).
__global__ __launch_bounds__(576) void k3_big(
    const uint16_t* __restrict__ HH, const uint16_t* __restrict__ HS,
    const float* __restrict__ h_dep, const float* __restrict__ partial,
    const float* __restrict__ s_hd, const float* __restrict__ s_hs,
    const float* __restrict__ s_ds,
    const float* __restrict__ bias, float* __restrict__ out) {
  __shared__ __align__(16) uint16_t HHt[96 * 256];   // 48 KB
  __shared__ __align__(16) uint16_t HSt[96 * 256];   // 48 KB
  __shared__ __align__(16) uint16_t cvec4[4 * 256];  // 2 KB
  __shared__ float chd4[4][96];
  __shared__ float sds4[4][96];
  const int d0 = blockIdx.x * 4, hb = blockIdx.y >> 1, sb = blockIdx.y & 1, b = blockIdx.z;
  const int tid = threadIdx.x;
  const int lane = tid & 63, w = tid >> 6;
  const int wh = w / 3, ws = w % 3;
  const int l31 = lane & 31, l5 = lane >> 5;

  // ---- prologue: tile loads + per-d vectors ----
  #pragma unroll
  for (int i = 0; i < 11; ++i) {
    const int slot = i * 576 + tid;
    if (slot < 3072) {
      const int row = slot >> 5, c = slot & 31;
      const uint16_t* src = HH + ((size_t)(b * SS + hb * 96 + row) << 8) + c * 8;
      __builtin_amdgcn_global_load_lds((const __attribute__((address_space(1))) void*)src,
          (__attribute__((address_space(3))) void*)(HHt + (size_t)slot * 8), 16, 0, 0);
    } else if (slot < 6144) {
      const int s2 = slot - 3072;
      const int row = s2 >> 5, c = s2 & 31;
      const uint16_t* src = HS + ((size_t)(b * SS + sb * 96 + row) << 8) + c * 8;
      __builtin_amdgcn_global_load_lds((const __attribute__((address_space(1))) void*)src,
          (__attribute__((address_space(3))) void*)(HSt + (size_t)s2 * 8), 16, 0, 0);
    }
  }
  if (tid < NI) {
    float wr = 0.f;
    #pragma unroll
    for (int q = 0; q < 8; ++q) wr += partial[8 * tid + q];
    #pragma unroll
    for (int dd = 0; dd < 4; ++dd)
      cvec4[dd * NI + tid] = f2h(wr * h_dep[(size_t)(b * SS + d0 + dd) * NI + tid]);
  }
  if (tid < 384) {
    const int dd = tid / 96, t = tid % 96;
    chd4[dd][t] = s_hd[(size_t)(b * SS + hb * 96 + t) * SS + (d0 + dd)];
    sds4[dd][t] = s_ds[(size_t)(b * SS + d0 + dd) * SS + sb * 96 + t];
  }
  __syncthreads();

  const float bias0 = bias[0];
  const int arow = wh * 32 + l31, amask = arow & 15;
  const int brow = ws * 32 + l31, bmask = brow & 15;
  const int abase = arow * 512;   // byte offset of row in HHt
  const int bbase = brow * 512;
  const int sloc = ws * 32 + l31;
  const int s = sb * 96 + sloc;

  for (int dd = 0; dd < 4; ++dd) {
    f32x16 acc = {};
    #pragma unroll
    for (int kh = 0; kh < 2; ++kh) {
      #pragma unroll
      for (int ks = 0; ks < 8; ++ks) {
        const int sl = ks * 2 + l5;
        union { f16x8 v; uint4 u; } A, C, R;
        A.v = *reinterpret_cast<const f16x8*>((const char*)HHt + abase + kh * 256 + ((sl ^ amask) << 4));
        C.v = *reinterpret_cast<const f16x8*>((const char*)cvec4 + dd * 512 + kh * 256 + (sl << 4));
        R.u.x = hmul2(A.u.x, C.u.x);
        R.u.y = hmul2(A.u.y, C.u.y);
        R.u.z = hmul2(A.u.z, C.u.z);
        R.u.w = hmul2(A.u.w, C.u.w);
        const f16x8 bf = *reinterpret_cast<const f16x8*>((const char*)HSt + bbase + kh * 256 + ((sl ^ bmask) << 4));
        acc = __builtin_amdgcn_mfma_f32_32x32x16_f16(R.v, bf, acc, 0, 0, 0);
      }
    }
    const int d = d0 + dd;
    const float dsv = sds4[dd][sloc];
    #pragma unroll
    for (int r = 0; r < 16; ++r) {
      const int hl = wh * 32 + (r & 3) + 8 * (r >> 2) + 4 * l5;
      const float v = acc[r] + chd4[dd][hl] + bias0
                    + s_hs[(size_t)(b * SS + hb * 96 + hl) * SS + s] + dsv;
      out[((size_t)(b * SS + hb * 96 + hl) * SS + d) * SS + s] = v;
    }
  }
}

extern "C" void kernel_launch(void* const* d_in, const int* in_sizes, int n_in,
                              void* d_out, int out_size, void* d_ws, size_t ws_size,
                              hipStream_t stream) {
  const float* h_head = (const float*)d_in[0];
  const float* h_dep  = (const float*)d_in[1];
  const float* h_sib  = (const float*)d_in[2];
  const float* W_tri  = (const float*)d_in[3];
  const float* U_hd   = (const float*)d_in[4];
  const float* V_hs   = (const float*)d_in[5];
  const float* Z_ds   = (const float*)d_in[6];
  const float* bias   = (const float*)d_in[7];
  float* out = (float*)d_out;

  float* ws = (float*)d_ws;
  float* partial = ws;          ws += 2048;
  float* s_hd    = ws;          ws += NB * SS * SS;
  float* s_hs    = ws;          ws += NB * SS * SS;
  float* s_ds    = ws;          ws += NB * SS * SS;
  uint16_t* HH   = (uint16_t*)ws;
  uint16_t* HD   = HH + NB * SS * NI;
  uint16_t* HS   = HD + NB * SS * NI;
  uint16_t* dU16 = HS + NB * SS * NI;
  uint16_t* T216 = dU16 + NB * SS * NI;
  uint16_t* TZ16 = T216 + NB * SS * NI;

  kA<<<2168, 256, 0, stream>>>(W_tri, h_head, h_dep, h_sib, U_hd, V_hs, Z_ds,
                               partial, HH, HD, HS, dU16, T216, TZ16);
  k_s2<<<dim3(3, NB), 384, 0, stream>>>(HH, HD, dU16, T216, TZ16, s_hd, s_hs, s_ds);
  k3_big<<<dim3(48, 4, NB), 576, 0, stream>>>(HH, HS, h_dep, partial,
                                              s_hd, s_hs, s_ds, bias, out);
}

// Round 24
// 71.754 us; speedup vs baseline: 2.6094x; 1.0461x over previous
//
#include <hip/hip_runtime.h>
#include <hip/hip_fp16.h>
#include <stdint.h>

#define NB 4
#define SS 192
#define NI 256

typedef __attribute__((ext_vector_type(8))) _Float16 f16x8;
typedef __attribute__((ext_vector_type(2))) __fp16 fp16v2;
typedef __attribute__((ext_vector_type(16))) float f32x16;

__device__ __forceinline__ uint16_t f2h(float f) {
  union { _Float16 h; uint16_t u; } t; t.h = (_Float16)f; return t.u;
}

__device__ __forceinline__ uint32_t cvt2(float lo, float hi) {
  union { fp16v2 h; uint32_t u; } t;
  t.h = __builtin_amdgcn_cvt_pkrtz(lo, hi);
  return t.u;
}

__device__ __forceinline__ uint4 pack8h(const float4 a, const float4 b) {
  uint4 r;
  r.x = cvt2(a.x, a.y);
  r.y = cvt2(a.z, a.w);
  r.z = cvt2(b.x, b.y);
  r.w = cvt2(b.z, b.w);
  return r;
}

__device__ __forceinline__ uint32_t hmul2(uint32_t x, uint32_t y) {
  union { uint32_t u; __half2 h; } a, b, c;
  a.u = x; b.u = y;
  c.h = __hmul2(a.h, b.h);
  return c.u;
}

// Canonical fp16 storage: row-major, 8-elem chunk c stored at position c ^ (row&15).
// (Each 128-col half is closed under the XOR -> linear copy of a half preserves it.)
// partial[] contract: 2048 chunks of 8192 floats; w_red[i] = sum(partial[8i..8i+7]).

// ---------------- K_A: s1-blocks (0..23) + HH/HD/HS converts (24..119) + W partials (120..2167) ----------------
__global__ __launch_bounds__(256) void kA(
    const float* __restrict__ W,
    const float* __restrict__ h_head, const float* __restrict__ h_dep, const float* __restrict__ h_sib,
    const float* __restrict__ U, const float* __restrict__ V, const float* __restrict__ Z,
    float* __restrict__ partial,
    uint16_t* __restrict__ HH, uint16_t* __restrict__ HD, uint16_t* __restrict__ HS,
    uint16_t* __restrict__ dU16, uint16_t* __restrict__ T216, uint16_t* __restrict__ TZ16) {
  const int bi = blockIdx.x, tid = threadIdx.x;

  if (bi >= 120) {
    __shared__ float red[4];
    const int c = bi - 120;
    const float4* pw = (const float4*)(W + (size_t)c * 8192);
    float4 a = {0.f, 0.f, 0.f, 0.f};
    #pragma unroll
    for (int it = 0; it < 8; ++it) {
      const float4 v = pw[it * 256 + tid];
      a.x += v.x; a.y += v.y; a.z += v.z; a.w += v.w;
    }
    float s = (a.x + a.y) + (a.z + a.w);
    for (int off = 32; off > 0; off >>= 1) s += __shfl_down(s, off, 64);
    if ((tid & 63) == 0) red[tid >> 6] = s;
    __syncthreads();
    if (tid == 0) partial[c] = red[0] + red[1] + red[2] + red[3];
    return;
  }
  if (bi >= 24) {
    const int rl = tid >> 5, c8 = tid & 31;
    const int g = (bi - 24) * 8 + rl;              // 0..767
    const int dst = g * 32 + (c8 ^ (g & 15));
    const int srci = g * 64 + c8 * 2;
    { const float4 x = ((const float4*)h_head)[srci], y = ((const float4*)h_head)[srci + 1];
      ((uint4*)HH)[dst] = pack8h(x, y); }
    { const float4 x = ((const float4*)h_dep)[srci], y = ((const float4*)h_dep)[srci + 1];
      ((uint4*)HD)[dst] = pack8h(x, y); }
    { const float4 x = ((const float4*)h_sib)[srci], y = ((const float4*)h_sib)[srci + 1];
      ((uint4*)HS)[dst] = pack8h(x, y); }
    return;
  }

  // ---- s1 block: dU/T2/TZ = A(192xK) x B(U/V/Z rows)^T, self-converting staging ----
  {
    __shared__ __align__(16) uint16_t Ah[192 * 128];   // 48 KB
    __shared__ __align__(16) uint16_t Bh[128 * 128];   // 32 KB
    const int which = bi >> 3, rem = bi & 7;
    const int b = rem >> 1, nt = rem & 1;
    const float* As = (which == 0) ? h_dep : h_sib;
    const float* Bs = (which == 0) ? U : (which == 1) ? V : Z;
    uint16_t* Os = (which == 0) ? dU16 : (which == 1) ? T216 : TZ16;
    const int lane = tid & 63, w = tid >> 6;
    const int l31 = lane & 31, l5 = lane >> 5;
    const int N0 = nt * 128;
    f32x16 acc[6] = {};

    #pragma unroll
    for (int kh = 0; kh < 2; ++kh) {
      const int kbase = kh * 128;
      if (kh) __syncthreads();
      #pragma unroll
      for (int i = 0; i < 12; ++i) {
        const int slot = i * 256 + tid;
        const int row = slot >> 4, ck = slot & 15;
        const float* sp = As + (size_t)(b * SS + row) * NI + kbase + ck * 8;
        const float4 x = *(const float4*)sp, y = *(const float4*)(sp + 4);
        *(uint4*)((char*)Ah + row * 256 + ((ck ^ (row & 15)) << 4)) = pack8h(x, y);
      }
      #pragma unroll
      for (int i = 0; i < 8; ++i) {
        const int slot = i * 256 + tid;
        const int row = slot >> 4, ck = slot & 15;
        const float* sp = Bs + (size_t)(N0 + row) * NI + kbase + ck * 8;
        const float4 x = *(const float4*)sp, y = *(const float4*)(sp + 4);
        *(uint4*)((char*)Bh + row * 256 + ((ck ^ (row & 15)) << 4)) = pack8h(x, y);
      }
      __syncthreads();
      const int brow = w * 32 + l31;
      const int bbyte = brow * 256;
      const int bmask = brow & 15;
      #pragma unroll
      for (int ks = 0; ks < 8; ++ks) {
        const int sl = ks * 2 + l5;
        f16x8 bf = *reinterpret_cast<const f16x8*>((const char*)Bh + bbyte + ((sl ^ bmask) << 4));
        #pragma unroll
        for (int mt = 0; mt < 6; ++mt) {
          const int ar = mt * 32 + l31;
          f16x8 af = *reinterpret_cast<const f16x8*>((const char*)Ah + ar * 256 + ((sl ^ (ar & 15)) << 4));
          acc[mt] = __builtin_amdgcn_mfma_f32_32x32x16_f16(af, bf, acc[mt], 0, 0, 0);
        }
      }
    }
    const int n = N0 + w * 32 + l31;
    const int nck = n >> 3, npos = n & 7;
    #pragma unroll
    for (int mt = 0; mt < 6; ++mt) {
      #pragma unroll
      for (int r = 0; r < 16; ++r) {
        const int m = mt * 32 + (r & 3) + 8 * (r >> 2) + 4 * l5;
        Os[(size_t)(b * SS + m) * NI + ((nck ^ (m & 15)) << 3) + npos] = f2h(acc[mt][r]);
      }
    }
  }
}

// ---------------- K2 stage-2: s_hd/s_hs/s_ds (192x192, K=256), MFMA ----------------
__global__ __launch_bounds__(384, 1) void k_s2(
    const uint16_t* __restrict__ HH, const uint16_t* __restrict__ HD,
    const uint16_t* __restrict__ dU16, const uint16_t* __restrict__ T216, const uint16_t* __restrict__ TZ16,
    float* __restrict__ s_hd, float* __restrict__ s_hs, float* __restrict__ s_ds) {
  __shared__ __align__(16) uint16_t Ah[192 * 128];   // 48 KB
  __shared__ __align__(16) uint16_t Bh[192 * 128];   // 48 KB
  const int which = blockIdx.x, b = blockIdx.y;
  const uint16_t* As = (which == 2) ? HD : HH;
  const uint16_t* Bs = (which == 0) ? dU16 : (which == 1) ? T216 : TZ16;
  float* Os = (which == 0) ? s_hd : (which == 1) ? s_hs : s_ds;
  const int tid = threadIdx.x, lane = tid & 63, w = tid >> 6;
  const int l31 = lane & 31, l5 = lane >> 5;
  f32x16 acc[6] = {};

  #pragma unroll
  for (int kh = 0; kh < 2; ++kh) {
    const int kbase = kh * 128;
    if (kh) __syncthreads();
    #pragma unroll
    for (int i = 0; i < 8; ++i) {
      const int slot = i * 384 + tid;
      const int row = slot >> 4, ck = slot & 15;
      const uint16_t* src = As + (size_t)(b * SS + row) * NI + kbase + ck * 8;
      __builtin_amdgcn_global_load_lds((const __attribute__((address_space(1))) void*)src,
          (__attribute__((address_space(3))) void*)(Ah + (size_t)slot * 8), 16, 0, 0);
    }
    #pragma unroll
    for (int i = 0; i < 8; ++i) {
      const int slot = i * 384 + tid;
      const int row = slot >> 4, ck = slot & 15;
      const uint16_t* src = Bs + (size_t)(b * SS + row) * NI + kbase + ck * 8;
      __builtin_amdgcn_global_load_lds((const __attribute__((address_space(1))) void*)src,
          (__attribute__((address_space(3))) void*)(Bh + (size_t)slot * 8), 16, 0, 0);
    }
    __syncthreads();
    const int brow = w * 32 + l31;
    const int bbyte = brow * 256;
    const int bmask = brow & 15;
    #pragma unroll
    for (int ks = 0; ks < 8; ++ks) {
      const int sl = ks * 2 + l5;
      f16x8 bf = *reinterpret_cast<const f16x8*>((const char*)Bh + bbyte + ((sl ^ bmask) << 4));
      #pragma unroll
      for (int mt = 0; mt < 6; ++mt) {
        const int ar = mt * 32 + l31;
        f16x8 af = *reinterpret_cast<const f16x8*>((const char*)Ah + ar * 256 + ((sl ^ (ar & 15)) << 4));
        acc[mt] = __builtin_amdgcn_mfma_f32_32x32x16_f16(af, bf, acc[mt], 0, 0, 0);
      }
    }
  }
  const int n = w * 32 + l31;
  #pragma unroll
  for (int mt = 0; mt < 6; ++mt) {
    #pragma unroll
    for (int r = 0; r < 16; ++r) {
      const int m = mt * 32 + (r & 3) + 8 * (r >> 2) + 4 * l5;
      Os[(size_t)(b * SS + m) * SS + n] = acc[mt][r];
    }
  }
}

// ---------------- K3: main GEMM — 96h x 192s, 9 waves, 2 acc/wave (1A+2B reads per 2 MFMAs) ----------------
// grid (192, 2, 4): x=d, y=hb, z=b. Wave (wh,wsi) owns s-strips wsi and wsi+3.
// LDS ~74 KB -> 2 blocks/CU. A staged once per (d,hb); chd_s + sds_s staged in prologue.
__global__ __launch_bounds__(576) void k3_big(
    const uint16_t* __restrict__ HH, const uint16_t* __restrict__ HS,
    const float* __restrict__ h_dep, const float* __restrict__ partial,
    const float* __restrict__ s_hd, const float* __restrict__ s_hs,
    const float* __restrict__ s_ds,
    const float* __restrict__ bias, float* __restrict__ out) {
  __shared__ __align__(16) uint16_t Atile[96 * 128];    // 24 KB
  __shared__ __align__(16) uint16_t Btile[SS * 128];    // 48 KB
  __shared__ uint16_t cvec[NI];
  __shared__ float chd_s[96];
  __shared__ float sds_s[SS];
  const int d = blockIdx.x, hb = blockIdx.y, b = blockIdx.z;
  const int tid = threadIdx.x;
  const int lane = tid & 63, w = tid >> 6;
  const int wh = w / 3, wsi = w % 3;
  const int l31 = lane & 31, l5 = lane >> 5;

  if (tid < NI) {
    float wr = 0.f;
    #pragma unroll
    for (int q = 0; q < 8; ++q) wr += partial[8 * tid + q];
    cvec[tid] = f2h(wr * h_dep[(size_t)(b * SS + d) * NI + tid]);
  } else if (tid < NI + 96) {
    const int t = tid - NI;
    chd_s[t] = s_hd[(size_t)(b * SS + hb * 96 + t) * SS + d];
  } else if (tid < NI + 96 + SS) {
    const int t = tid - (NI + 96);
    sds_s[t] = s_ds[(size_t)(b * SS + d) * SS + t];
  }
  __syncthreads();

  f32x16 acc0 = {}, acc1 = {};

  #pragma unroll
  for (int half = 0; half < 2; ++half) {
    const int kbase = half * 128;
    if (half) __syncthreads();
    // B-tile: all 192 HS rows (swizzled storage half -> linear LDS copy)
    #pragma unroll
    for (int i = 0; i < 6; ++i) {
      const int slot = i * 576 + tid;
      if (slot < 3072) {
        const int row = slot >> 4;
        const uint16_t* src = HS + ((size_t)(b * SS + row) << 8) + kbase + (slot & 15) * 8;
        __builtin_amdgcn_global_load_lds(
            (const __attribute__((address_space(1))) void*)src,
            (__attribute__((address_space(3))) void*)(Btile + (size_t)slot * 8),
            16, 0, 0);
      }
    }
    // A-tile: HH (swizzled storage) * cvec -> LDS (linear write = swizzled layout)
    #pragma unroll
    for (int i = 0; i < 3; ++i) {
      const int slot = i * 576 + tid;
      if (slot < 1536) {
        const int row = slot >> 4;
        const int kc = slot & 15;
        const int lcl = kc ^ (row & 15);
        const uint4 cv4 = *(const uint4*)(cvec + kbase + lcl * 8);
        const uint4 hh4 = *(const uint4*)(HH + ((size_t)(b * SS + hb * 96 + row) << 8) + kbase + kc * 8);
        uint4 a4;
        a4.x = hmul2(hh4.x, cv4.x);
        a4.y = hmul2(hh4.y, cv4.y);
        a4.z = hmul2(hh4.z, cv4.z);
        a4.w = hmul2(hh4.w, cv4.w);
        *(uint4*)((char*)Atile + (size_t)slot * 16) = a4;
      }
    }
    __syncthreads();
    const int arow = wh * 32 + l31;
    const int abyte = arow * 256;
    const int amask = arow & 15;
    const int brow0 = wsi * 32 + l31;
    const int brow1 = brow0 + 96;
    const int bbyte0 = brow0 * 256, bmask0 = brow0 & 15;
    const int bbyte1 = brow1 * 256, bmask1 = brow1 & 15;
    #pragma unroll
    for (int ks = 0; ks < 8; ++ks) {
      const int sl = ks * 2 + l5;
      f16x8 af = *reinterpret_cast<const f16x8*>((const char*)Atile + abyte + ((sl ^ amask) << 4));
      f16x8 bf0 = *reinterpret_cast<const f16x8*>((const char*)Btile + bbyte0 + ((sl ^ bmask0) << 4));
      f16x8 bf1 = *reinterpret_cast<const f16x8*>((const char*)Btile + bbyte1 + ((sl ^ bmask1) << 4));
      acc0 = __builtin_amdgcn_mfma_f32_32x32x16_f16(af, bf0, acc0, 0, 0, 0);
      acc1 = __builtin_amdgcn_mfma_f32_32x32x16_f16(af, bf1, acc1, 0, 0, 0);
    }
  }

  const float bias0 = bias[0];
  #pragma unroll
  for (int t = 0; t < 2; ++t) {
    const int s = wsi * 32 + l31 + t * 96;
    const float dsv = sds_s[s];
    const f32x16 a = t ? acc1 : acc0;
    #pragma unroll
    for (int r = 0; r < 16; ++r) {
      const int hl = wh * 32 + (r & 3) + 8 * (r >> 2) + 4 * l5;
      const float v = a[r] + chd_s[hl] + bias0
                    + s_hs[(size_t)(b * SS + hb * 96 + hl) * SS + s] + dsv;
      out[((size_t)(b * SS + hb * 96 + hl) * SS + d) * SS + s] = v;
    }
  }
}

extern "C" void kernel_launch(void* const* d_in, const int* in_sizes, int n_in,
                              void* d_out, int out_size, void* d_ws, size_t ws_size,
                              hipStream_t stream) {
  const float* h_head = (const float*)d_in[0];
  const float* h_dep  = (const float*)d_in[1];
  const float* h_sib  = (const float*)d_in[2];
  const float* W_tri  = (const float*)d_in[3];
  const float* U_hd   = (const float*)d_in[4];
  const float* V_hs   = (const float*)d_in[5];
  const float* Z_ds   = (const float*)d_in[6];
  const float* bias   = (const float*)d_in[7];
  float* out = (float*)d_out;

  float* ws = (float*)d_ws;
  float* partial = ws;          ws += 2048;
  float* s_hd    = ws;          ws += NB * SS * SS;
  float* s_hs    = ws;          ws += NB * SS * SS;
  float* s_ds    = ws;          ws += NB * SS * SS;
  uint16_t* HH   = (uint16_t*)ws;
  uint16_t* HD   = HH + NB * SS * NI;
  uint16_t* HS   = HD + NB * SS * NI;
  uint16_t* dU16 = HS + NB * SS * NI;
  uint16_t* T216 = dU16 + NB * SS * NI;
  uint16_t* TZ16 = T216 + NB * SS * NI;

  kA<<<2168, 256, 0, stream>>>(W_tri, h_head, h_dep, h_sib, U_hd, V_hs, Z_ds,
                               partial, HH, HD, HS, dU16, T216, TZ16);
  k_s2<<<dim3(3, NB), 384, 0, stream>>>(HH, HD, dU16, T216, TZ16, s_hd, s_hs, s_ds);
  k3_big<<<dim3(SS, 2, NB), 576, 0, stream>>>(HH, HS, h_dep, partial,
                                              s_hd, s_hs, s_ds, bias, out);
}

// Round 25
// 63.958 us; speedup vs baseline: 2.9275x; 1.1219x over previous
//
#include <hip/hip_runtime.h>
#include <hip/hip_fp16.h>
#include <stdint.h>

#define NB 4
#define SS 192
#define NI 256

typedef __attribute__((ext_vector_type(8))) _Float16 f16x8;
typedef __attribute__((ext_vector_type(2))) __fp16 fp16v2;
typedef __attribute__((ext_vector_type(16))) float f32x16;

__device__ __forceinline__ uint16_t f2h(float f) {
  union { _Float16 h; uint16_t u; } t; t.h = (_Float16)f; return t.u;
}

__device__ __forceinline__ uint32_t cvt2(float lo, float hi) {
  union { fp16v2 h; uint32_t u; } t;
  t.h = __builtin_amdgcn_cvt_pkrtz(lo, hi);
  return t.u;
}

__device__ __forceinline__ uint4 pack8h(const float4 a, const float4 b) {
  uint4 r;
  r.x = cvt2(a.x, a.y);
  r.y = cvt2(a.z, a.w);
  r.z = cvt2(b.x, b.y);
  r.w = cvt2(b.z, b.w);
  return r;
}

__device__ __forceinline__ uint32_t hmul2(uint32_t x, uint32_t y) {
  union { uint32_t u; __half2 h; } a, b, c;
  a.u = x; b.u = y;
  c.h = __hmul2(a.h, b.h);
  return c.u;
}

// Canonical fp16 storage: row-major, 8-elem chunk c stored at position c ^ (row&15).
// CV is stored LOGICAL (unswizzled). s_hdT is s_hd transposed: [d][h].
// partial[] contract: 2048 chunks of 8192 floats; w_red[i] = sum(partial[8i..8i+7]).

// ---------------- K_A: s1-blocks (0..23) + HH/HD/HS converts (24..119) + W partials (120..2167) ----------------
__global__ __launch_bounds__(256) void kA(
    const float* __restrict__ W,
    const float* __restrict__ h_head, const float* __restrict__ h_dep, const float* __restrict__ h_sib,
    const float* __restrict__ U, const float* __restrict__ V, const float* __restrict__ Z,
    float* __restrict__ partial,
    uint16_t* __restrict__ HH, uint16_t* __restrict__ HD, uint16_t* __restrict__ HS,
    uint16_t* __restrict__ dU16, uint16_t* __restrict__ T216, uint16_t* __restrict__ TZ16) {
  const int bi = blockIdx.x, tid = threadIdx.x;

  if (bi >= 120) {
    __shared__ float red[4];
    const int c = bi - 120;
    const float4* pw = (const float4*)(W + (size_t)c * 8192);
    float4 a = {0.f, 0.f, 0.f, 0.f};
    #pragma unroll
    for (int it = 0; it < 8; ++it) {
      const float4 v = pw[it * 256 + tid];
      a.x += v.x; a.y += v.y; a.z += v.z; a.w += v.w;
    }
    float s = (a.x + a.y) + (a.z + a.w);
    for (int off = 32; off > 0; off >>= 1) s += __shfl_down(s, off, 64);
    if ((tid & 63) == 0) red[tid >> 6] = s;
    __syncthreads();
    if (tid == 0) partial[c] = red[0] + red[1] + red[2] + red[3];
    return;
  }
  if (bi >= 24) {
    const int rl = tid >> 5, c8 = tid & 31;
    const int g = (bi - 24) * 8 + rl;              // 0..767
    const int dst = g * 32 + (c8 ^ (g & 15));
    const int srci = g * 64 + c8 * 2;
    { const float4 x = ((const float4*)h_head)[srci], y = ((const float4*)h_head)[srci + 1];
      ((uint4*)HH)[dst] = pack8h(x, y); }
    { const float4 x = ((const float4*)h_dep)[srci], y = ((const float4*)h_dep)[srci + 1];
      ((uint4*)HD)[dst] = pack8h(x, y); }
    { const float4 x = ((const float4*)h_sib)[srci], y = ((const float4*)h_sib)[srci + 1];
      ((uint4*)HS)[dst] = pack8h(x, y); }
    return;
  }

  // ---- s1 block: dU/T2/TZ = A(192xK) x B(U/V/Z rows)^T, self-converting staging ----
  {
    __shared__ __align__(16) uint16_t Ah[192 * 128];   // 48 KB
    __shared__ __align__(16) uint16_t Bh[128 * 128];   // 32 KB
    const int which = bi >> 3, rem = bi & 7;
    const int b = rem >> 1, nt = rem & 1;
    const float* As = (which == 0) ? h_dep : h_sib;
    const float* Bs = (which == 0) ? U : (which == 1) ? V : Z;
    uint16_t* Os = (which == 0) ? dU16 : (which == 1) ? T216 : TZ16;
    const int lane = tid & 63, w = tid >> 6;
    const int l31 = lane & 31, l5 = lane >> 5;
    const int N0 = nt * 128;
    f32x16 acc[6] = {};

    #pragma unroll
    for (int kh = 0; kh < 2; ++kh) {
      const int kbase = kh * 128;
      if (kh) __syncthreads();
      #pragma unroll
      for (int i = 0; i < 12; ++i) {
        const int slot = i * 256 + tid;
        const int row = slot >> 4, ck = slot & 15;
        const float* sp = As + (size_t)(b * SS + row) * NI + kbase + ck * 8;
        const float4 x = *(const float4*)sp, y = *(const float4*)(sp + 4);
        *(uint4*)((char*)Ah + row * 256 + ((ck ^ (row & 15)) << 4)) = pack8h(x, y);
      }
      #pragma unroll
      for (int i = 0; i < 8; ++i) {
        const int slot = i * 256 + tid;
        const int row = slot >> 4, ck = slot & 15;
        const float* sp = Bs + (size_t)(N0 + row) * NI + kbase + ck * 8;
        const float4 x = *(const float4*)sp, y = *(const float4*)(sp + 4);
        *(uint4*)((char*)Bh + row * 256 + ((ck ^ (row & 15)) << 4)) = pack8h(x, y);
      }
      __syncthreads();
      const int brow = w * 32 + l31;
      const int bbyte = brow * 256;
      const int bmask = brow & 15;
      #pragma unroll
      for (int ks = 0; ks < 8; ++ks) {
        const int sl = ks * 2 + l5;
        f16x8 bf = *reinterpret_cast<const f16x8*>((const char*)Bh + bbyte + ((sl ^ bmask) << 4));
        #pragma unroll
        for (int mt = 0; mt < 6; ++mt) {
          const int ar = mt * 32 + l31;
          f16x8 af = *reinterpret_cast<const f16x8*>((const char*)Ah + ar * 256 + ((sl ^ (ar & 15)) << 4));
          acc[mt] = __builtin_amdgcn_mfma_f32_32x32x16_f16(af, bf, acc[mt], 0, 0, 0);
        }
      }
    }
    const int n = N0 + w * 32 + l31;
    const int nck = n >> 3, npos = n & 7;
    #pragma unroll
    for (int mt = 0; mt < 6; ++mt) {
      #pragma unroll
      for (int r = 0; r < 16; ++r) {
        const int m = mt * 32 + (r & 3) + 8 * (r >> 2) + 4 * l5;
        Os[(size_t)(b * SS + m) * NI + ((nck ^ (m & 15)) << 3) + npos] = f2h(acc[mt][r]);
      }
    }
  }
}

// ---------------- K2: s_hdT (which=0, swapped operands) / s_hs / s_ds + CV precompute (which=3) ----------------
__global__ __launch_bounds__(384, 1) void k_s2(
    const uint16_t* __restrict__ HH, const uint16_t* __restrict__ HD,
    const uint16_t* __restrict__ dU16, const uint16_t* __restrict__ T216, const uint16_t* __restrict__ TZ16,
    const float* __restrict__ h_dep, const float* __restrict__ partial,
    float* __restrict__ s_hdT, float* __restrict__ s_hs, float* __restrict__ s_ds,
    uint16_t* __restrict__ CV) {
  __shared__ __align__(16) uint16_t Ah[192 * 128];   // 48 KB
  __shared__ __align__(16) uint16_t Bh[192 * 128];   // 48 KB
  const int which = blockIdx.x, b = blockIdx.y;
  const int tid = threadIdx.x, lane = tid & 63, w = tid >> 6;
  const int l31 = lane & 31, l5 = lane >> 5;

  if (which == 3) {
    // ---- CV[b,d,k] = fp16(w_red[k] * h_dep[b,d,k]), logical layout ----
    __shared__ float wred[NI];
    if (tid < NI) {
      float wr = 0.f;
      #pragma unroll
      for (int q = 0; q < 8; ++q) wr += partial[8 * tid + q];
      wred[tid] = wr;
    }
    __syncthreads();
    #pragma unroll
    for (int i = 0; i < 16; ++i) {
      const int slot = i * 384 + tid;              // 6144 slots = 192 rows x 32 chunks
      const int d = slot >> 5, c8 = slot & 31;
      const float* sp = h_dep + (size_t)(b * SS + d) * NI + c8 * 8;
      float4 x = *(const float4*)sp, y = *(const float4*)(sp + 4);
      const float* wp = wred + c8 * 8;
      x.x *= wp[0]; x.y *= wp[1]; x.z *= wp[2]; x.w *= wp[3];
      y.x *= wp[4]; y.y *= wp[5]; y.z *= wp[6]; y.w *= wp[7];
      ((uint4*)CV)[(size_t)(b * SS + d) * 32 + c8] = pack8h(x, y);
    }
    return;
  }

  // which==0: s_hdT[d][h] = dU x HH^T (swapped operands — free transpose)
  const uint16_t* As = (which == 0) ? dU16 : (which == 2) ? HD : HH;
  const uint16_t* Bs = (which == 0) ? HH : (which == 1) ? T216 : TZ16;
  float* Os = (which == 0) ? s_hdT : (which == 1) ? s_hs : s_ds;
  f32x16 acc[6] = {};

  #pragma unroll
  for (int kh = 0; kh < 2; ++kh) {
    const int kbase = kh * 128;
    if (kh) __syncthreads();
    #pragma unroll
    for (int i = 0; i < 8; ++i) {
      const int slot = i * 384 + tid;
      const int row = slot >> 4, ck = slot & 15;
      const uint16_t* src = As + (size_t)(b * SS + row) * NI + kbase + ck * 8;
      __builtin_amdgcn_global_load_lds((const __attribute__((address_space(1))) void*)src,
          (__attribute__((address_space(3))) void*)(Ah + (size_t)slot * 8), 16, 0, 0);
    }
    #pragma unroll
    for (int i = 0; i < 8; ++i) {
      const int slot = i * 384 + tid;
      const int row = slot >> 4, ck = slot & 15;
      const uint16_t* src = Bs + (size_t)(b * SS + row) * NI + kbase + ck * 8;
      __builtin_amdgcn_global_load_lds((const __attribute__((address_space(1))) void*)src,
          (__attribute__((address_space(3))) void*)(Bh + (size_t)slot * 8), 16, 0, 0);
    }
    __syncthreads();
    const int brow = w * 32 + l31;
    const int bbyte = brow * 256;
    const int bmask = brow & 15;
    #pragma unroll
    for (int ks = 0; ks < 8; ++ks) {
      const int sl = ks * 2 + l5;
      f16x8 bf = *reinterpret_cast<const f16x8*>((const char*)Bh + bbyte + ((sl ^ bmask) << 4));
      #pragma unroll
      for (int mt = 0; mt < 6; ++mt) {
        const int ar = mt * 32 + l31;
        f16x8 af = *reinterpret_cast<const f16x8*>((const char*)Ah + ar * 256 + ((sl ^ (ar & 15)) << 4));
        acc[mt] = __builtin_amdgcn_mfma_f32_32x32x16_f16(af, bf, acc[mt], 0, 0, 0);
      }
    }
  }
  const int n = w * 32 + l31;
  #pragma unroll
  for (int mt = 0; mt < 6; ++mt) {
    #pragma unroll
    for (int r = 0; r < 16; ++r) {
      const int m = mt * 32 + (r & 3) + 8 * (r >> 2) + 4 * l5;
      Os[(size_t)(b * SS + m) * SS + n] = acc[mt][r];
    }
  }
}

// ---------------- K3: main GEMM — R21 geometry (96h x 96s, 9 waves, 3 blk/CU), contiguous prologue ----------------
__global__ __launch_bounds__(576) void k3_big(
    const uint16_t* __restrict__ HH, const uint16_t* __restrict__ HS,
    const uint16_t* __restrict__ CV, const float* __restrict__ s_hdT,
    const float* __restrict__ s_hs, const float* __restrict__ s_ds,
    const float* __restrict__ bias, float* __restrict__ out) {
  __shared__ __align__(16) uint16_t Btile[96 * 128];   // 24 KB
  __shared__ __align__(16) uint16_t Atile[96 * 128];   // 24 KB
  __shared__ __align__(16) uint16_t cvec[NI];
  __shared__ float chd_s[96];
  const int d = blockIdx.x, hb = blockIdx.y >> 1, sb = blockIdx.y & 1, b = blockIdx.z;
  const int tid = threadIdx.x;
  const int lane = tid & 63, w = tid >> 6;
  const int wh = w / 3, ws = w % 3;
  const int l31 = lane & 31, l5 = lane >> 5;

  // prologue: ALL contiguous — 32 uint4 (cvec) + 96 floats (chd row from s_hdT)
  if (tid < 32) {
    ((uint4*)cvec)[tid] = ((const uint4*)(CV + (size_t)(b * SS + d) * NI))[tid];
  } else if (tid >= 64 && tid < 160) {
    const int t = tid - 64;
    chd_s[t] = s_hdT[(size_t)(b * SS + d) * SS + hb * 96 + t];
  }
  __syncthreads();

  f32x16 acc = {};

  #pragma unroll
  for (int half = 0; half < 2; ++half) {
    const int kbase = half * 128;
    if (half) __syncthreads();
    #pragma unroll
    for (int i = 0; i < 3; ++i) {
      const int slot = i * 576 + tid;
      if (slot < 1536) {
        const int row = slot >> 4;
        const uint16_t* src = HS + ((size_t)(b * SS + sb * 96 + row) << 8) + kbase + (slot & 15) * 8;
        __builtin_amdgcn_global_load_lds(
            (const __attribute__((address_space(1))) void*)src,
            (__attribute__((address_space(3))) void*)(Btile + (size_t)slot * 8),
            16, 0, 0);
      }
    }
    #pragma unroll
    for (int i = 0; i < 3; ++i) {
      const int slot = i * 576 + tid;
      if (slot < 1536) {
        const int row = slot >> 4;
        const int kc = slot & 15;
        const int lcl = kc ^ (row & 15);
        const uint4 cv4 = *(const uint4*)(cvec + kbase + lcl * 8);
        const uint4 hh4 = *(const uint4*)(HH + ((size_t)(b * SS + hb * 96 + row) << 8) + kbase + kc * 8);
        uint4 a4;
        a4.x = hmul2(hh4.x, cv4.x);
        a4.y = hmul2(hh4.y, cv4.y);
        a4.z = hmul2(hh4.z, cv4.z);
        a4.w = hmul2(hh4.w, cv4.w);
        *(uint4*)((char*)Atile + (size_t)slot * 16) = a4;
      }
    }
    __syncthreads();
    const int arow = wh * 32 + l31;
    const int abyte = arow * 256;
    const int amask = arow & 15;
    const int brow = ws * 32 + l31;
    const int bbyte = brow * 256;
    const int bmask = brow & 15;
    #pragma unroll
    for (int ks = 0; ks < 8; ++ks) {
      const int sl = ks * 2 + l5;
      f16x8 af = *reinterpret_cast<const f16x8*>((const char*)Atile + abyte + ((sl ^ amask) << 4));
      f16x8 bf = *reinterpret_cast<const f16x8*>((const char*)Btile + bbyte + ((sl ^ bmask) << 4));
      acc = __builtin_amdgcn_mfma_f32_32x32x16_f16(af, bf, acc, 0, 0, 0);
    }
  }

  const float bias0 = bias[0];
  const int s = sb * 96 + ws * 32 + l31;
  const float dsv = s_ds[(size_t)(b * SS + d) * SS + s];
  #pragma unroll
  for (int r = 0; r < 16; ++r) {
    const int hl = wh * 32 + (r & 3) + 8 * (r >> 2) + 4 * l5;
    const float v = acc[r] + chd_s[hl] + bias0
                  + s_hs[(size_t)(b * SS + hb * 96 + hl) * SS + s] + dsv;
    out[((size_t)(b * SS + hb * 96 + hl) * SS + d) * SS + s] = v;
  }
}

extern "C" void kernel_launch(void* const* d_in, const int* in_sizes, int n_in,
                              void* d_out, int out_size, void* d_ws, size_t ws_size,
                              hipStream_t stream) {
  const float* h_head = (const float*)d_in[0];
  const float* h_dep  = (const float*)d_in[1];
  const float* h_sib  = (const float*)d_in[2];
  const float* W_tri  = (const float*)d_in[3];
  const float* U_hd   = (const float*)d_in[4];
  const float* V_hs   = (const float*)d_in[5];
  const float* Z_ds   = (const float*)d_in[6];
  const float* bias   = (const float*)d_in[7];
  float* out = (float*)d_out;

  float* ws = (float*)d_ws;
  float* partial = ws;          ws += 2048;
  float* s_hdT   = ws;          ws += NB * SS * SS;
  float* s_hs    = ws;          ws += NB * SS * SS;
  float* s_ds    = ws;          ws += NB * SS * SS;
  uint16_t* HH   = (uint16_t*)ws;
  uint16_t* HD   = HH + NB * SS * NI;
  uint16_t* HS   = HD + NB * SS * NI;
  uint16_t* dU16 = HS + NB * SS * NI;
  uint16_t* T216 = dU16 + NB * SS * NI;
  uint16_t* TZ16 = T216 + NB * SS * NI;
  uint16_t* CV   = TZ16 + NB * SS * NI;

  kA<<<2168, 256, 0, stream>>>(W_tri, h_head, h_dep, h_sib, U_hd, V_hs, Z_ds,
                               partial, HH, HD, HS, dU16, T216, TZ16);
  k_s2<<<dim3(4, NB), 384, 0, stream>>>(HH, HD, dU16, T216, TZ16, h_dep, partial,
                                        s_hdT, s_hs, s_ds, CV);
  k3_big<<<dim3(SS, 4, NB), 576, 0, stream>>>(HH, HS, CV, s_hdT,
                                              s_hs, s_ds, bias, out);
}